// Round 19
// baseline (340.610 us; speedup 1.0000x reference)
//
#include <hip/hip_runtime.h>
#include <hip/hip_bf16.h>
#include <math.h>

#define N_TOK   32768
#define DIM     256
#define KC      8192

// output layout (flat f32, reference tuple order)
#define OUT_ZQ    0
#define OUT_IDX   8388608          // N_TOK*DIM
#define OUT_LOSS  8421376          // +N_TOK
#define OUT_NEMB  8421377          // +1   (NOTE: odd -> scalar stores only)
#define OUT_CS    10518529         // +KC*DIM
#define OUT_SUM   10526721         // +KC  (odd -> scalar stores only)

#define MARGIN  8e-3f              // validated for 1-term phase-1 (R9/R14/R15/R16)
#define FLAGCAP 16384

typedef __attribute__((ext_vector_type(8))) __bf16 bf16x8;
typedef __attribute__((ext_vector_type(4))) float f32x4;

__device__ __forceinline__ void gload16(const void* g, void* l) {
  __builtin_amdgcn_global_load_lds((const __attribute__((address_space(1))) void*)g,
                                   (__attribute__((address_space(3))) void*)l, 16, 0, 0);
}

// ---- numpy pairwise sum-of-squares emulation (validated R3) ----
__device__ __forceinline__ float np_sumsq256(const float* __restrict__ p, int lane) {
  const int l = lane & 15;
  const int h = l >> 3;
  const int j = l & 7;
  const float* a = p + h * 128 + j;
  float x = a[0];
  float r = __fmul_rn(x, x);
  #pragma unroll
  for (int i = 1; i < 16; ++i) {
    x = a[8 * i];
    r = __fadd_rn(r, __fmul_rn(x, x));
  }
  r = __fadd_rn(r, __shfl_down(r, 1));
  r = __fadd_rn(r, __shfl_down(r, 2));
  r = __fadd_rn(r, __shfl_down(r, 4));
  float hi = __shfl(r, (lane & 48) | 8);
  return __fadd_rn(r, hi);
}

// esq (numpy-exact) + esp2 (LDS-image pre-tile) + hist/cnt init (fused)
__global__ void vq_prep(const float* __restrict__ emb, float* __restrict__ esq,
                        short* __restrict__ esp2, int* __restrict__ hist,
                        int* __restrict__ cnt) {
  const int t = threadIdx.x;
  const int code = blockIdx.x * 8 + (t >> 5);
  const int p = t & 31, j = p >> 2, g = p & 3;
  const float* src = emb + (size_t)code * DIM + j * 32 + g * 8;
  const float4 v0 = *(const float4*)src;
  const float4 v1 = *(const float4*)(src + 4);
  const float xf[8] = {v0.x, v0.y, v0.z, v0.w, v1.x, v1.y, v1.z, v1.w};
  bf16x8 hb;
  #pragma unroll
  for (int e = 0; e < 8; ++e) hb[e] = (__bf16)xf[e];
  const int c = code & 15, sub = (code >> 4) & 3, ct = code >> 6;
  const int slot = (g + (c >> 1)) & 3;
  char* dst = (char*)esp2 + (size_t)ct * 32768 + ((sub * 8 + j) << 10) + c * 64 + slot * 16;
  *(bf16x8*)dst = hb;
  if (t < 128) {
    const int code2 = blockIdx.x * 8 + (t >> 4);
    const float s = np_sumsq256(emb + (size_t)code2 * DIM, t & 63);
    if ((t & 15) == 0) esq[code2] = s;
  }
  if (blockIdx.x < 32) hist[blockIdx.x * 256 + t] = 0;
  if (blockIdx.x == 0 && t == 0) cnt[0] = 0;
}

// 64x64-tile transpose: embT[k][code] = emb[code][k]
__global__ void vq_transpose(const float* __restrict__ emb, float* __restrict__ embT) {
  __shared__ float t[64][65];
  const int tid = threadIdx.x;
  const int bc  = blockIdx.x & 127;
  const int bk  = blockIdx.x >> 7;
  const int cc0 = bc << 6, kc0 = bk << 6;
  const int col = tid & 63, qr = tid >> 6;
  #pragma unroll
  for (int i = 0; i < 16; ++i) {
    const int row = i * 4 + qr;
    t[row][col] = emb[(size_t)(cc0 + row) * DIM + kc0 + col];
  }
  __syncthreads();
  #pragma unroll
  for (int i = 0; i < 16; ++i) {
    const int krow = i * 4 + qr;
    embT[(size_t)(kc0 + krow) * KC + cc0 + col] = t[col][krow];
  }
}

// ---- MFMA argmin: 2048 blocks (256 row-tiles of 128 rows x 8 code-eighths).
// 1-term (z_hi.e_hi), 32 rows/wave (VGPR ~64 -> 8 waves/SIMD tier), 32 units,
// 2x16KB dbuf (32KB LDS -> 5 blocks/CU cap). Deep grid for barrier overlap.
__launch_bounds__(256, 4)
__global__ void vq_mfma(const float* __restrict__ z,
                        const short* __restrict__ esp,
                        const float* __restrict__ esq,
                        float* __restrict__ pb1,
                        int* __restrict__ pi1,
                        float* __restrict__ pb2) {
  __shared__ __align__(16) char lds[32768];
  const int tid  = threadIdx.x;
  const int lane = tid & 63;
  const int w    = tid >> 6;
  const int l15  = lane & 15;
  const int g    = lane >> 4;
  const int rt   = blockIdx.x >> 3;
  const int kh   = blockIdx.x & 7;
  const int rowbase = rt * 128 + w * 32;
  const int u0 = kh * 32, u1 = u0 + 32;
  const int gx = (g + (l15 >> 1)) & 3;     // conflict-free read slot (R8-verified)
  const char* espb = (const char*)esp;

  // linear copy of one 16KB unit: wave w stages subtiles w*4..w*4+3
#define STAGE(U, BUFB)                                                           \
  {                                                                              \
    _Pragma("unroll")                                                            \
    for (int q_ = 0; q_ < 4; ++q_) {                                             \
      const int so_ = (((w << 2) + q_) << 10);                                   \
      gload16(espb + (size_t)(U) * 16384 + so_ + (lane << 4),                    \
              (void*)(lds + (BUFB) + so_));                                      \
    }                                                                            \
  }

  STAGE(u0, 0);

  // A: 32 z rows -> bf16 hi fragments only (~64 VGPR total, R15-proven)
  bf16x8 Ahi[2][8];
  #pragma unroll
  for (int s = 0; s < 2; ++s) {
    const float* zr = z + (size_t)(rowbase + s * 16 + l15) * DIM + g * 8;
    #pragma unroll
    for (int c = 0; c < 8; ++c) {
      const float4 v0 = *(const float4*)(zr + c * 32);
      const float4 v1 = *(const float4*)(zr + c * 32 + 4);
      const float xf[8] = {v0.x, v0.y, v0.z, v0.w, v1.x, v1.y, v1.z, v1.w};
      #pragma unroll
      for (int e = 0; e < 8; ++e) Ahi[s][c][e] = (__bf16)xf[e];
    }
  }

  __syncthreads();   // unit u0 staged

  float b1[2][4], b2[2][4];
  int   i1[2][4];
  #pragma unroll
  for (int s = 0; s < 2; ++s)
    #pragma unroll
    for (int r = 0; r < 4; ++r) { b1[s][r] = 3.4e38f; b2[s][r] = 3.4e38f; i1[s][r] = 0x7fffffff; }

  int bp = 0;
  for (int u = u0; u < u1; ++u) {
    if (u + 1 < u1) STAGE(u + 1, (bp ^ 1) << 14);   // issue early

    const float eq0 = esq[(u << 5) + l15];
    const float eq1 = esq[(u << 5) + 16 + l15];

    f32x4 acc00 = (f32x4){0.f, 0.f, 0.f, 0.f};
    f32x4 acc01 = (f32x4){0.f, 0.f, 0.f, 0.f};
    f32x4 acc10 = (f32x4){0.f, 0.f, 0.f, 0.f};
    f32x4 acc11 = (f32x4){0.f, 0.f, 0.f, 0.f};

    {
      const char* base = lds + (bp << 14);
      #pragma unroll
      for (int j_ = 0; j_ < 8; ++j_) {
        const char* bq_ = base + (j_ << 10) + (l15 << 6) + (gx << 4);
        const bf16x8 bF0 = *(const bf16x8*)(bq_);
        const bf16x8 bF1 = *(const bf16x8*)(bq_ + 8192);
        acc00 = __builtin_amdgcn_mfma_f32_16x16x32_bf16(Ahi[0][j_], bF0, acc00, 0, 0, 0);
        acc01 = __builtin_amdgcn_mfma_f32_16x16x32_bf16(Ahi[0][j_], bF1, acc01, 0, 0, 0);
        acc10 = __builtin_amdgcn_mfma_f32_16x16x32_bf16(Ahi[1][j_], bF0, acc10, 0, 0, 0);
        acc11 = __builtin_amdgcn_mfma_f32_16x16x32_bf16(Ahi[1][j_], bF1, acc11, 0, 0, 0);
      }
    }

    // epilogue: score = esq - 2*(z_hi.e_hi); track (min, idx) + 2nd-min value
    const int code0 = (u << 5) + l15;
    const int code1 = code0 + 16;
    #pragma unroll
    for (int r = 0; r < 4; ++r) {
      const float sc = fmaf(-2.f, acc00[r], eq0);
      const bool lt = sc < b1[0][r];
      b2[0][r] = fminf(b2[0][r], fmaxf(sc, b1[0][r]));
      i1[0][r] = lt ? code0 : i1[0][r];
      b1[0][r] = fminf(b1[0][r], sc);
    }
    #pragma unroll
    for (int r = 0; r < 4; ++r) {
      const float sc = fmaf(-2.f, acc01[r], eq1);
      const bool lt = sc < b1[0][r];
      b2[0][r] = fminf(b2[0][r], fmaxf(sc, b1[0][r]));
      i1[0][r] = lt ? code1 : i1[0][r];
      b1[0][r] = fminf(b1[0][r], sc);
    }
    #pragma unroll
    for (int r = 0; r < 4; ++r) {
      const float sc = fmaf(-2.f, acc10[r], eq0);
      const bool lt = sc < b1[1][r];
      b2[1][r] = fminf(b2[1][r], fmaxf(sc, b1[1][r]));
      i1[1][r] = lt ? code0 : i1[1][r];
      b1[1][r] = fminf(b1[1][r], sc);
    }
    #pragma unroll
    for (int r = 0; r < 4; ++r) {
      const float sc = fmaf(-2.f, acc11[r], eq1);
      const bool lt = sc < b1[1][r];
      b2[1][r] = fminf(b2[1][r], fmaxf(sc, b1[1][r]));
      i1[1][r] = lt ? code1 : i1[1][r];
      b1[1][r] = fminf(b1[1][r], sc);
    }
    __syncthreads();   // next unit staged; current buf reads done
    bp ^= 1;
  }

  // merge across the 16 lanes sharing each output row; write partials
  #pragma unroll
  for (int s = 0; s < 2; ++s) {
    #pragma unroll
    for (int r = 0; r < 4; ++r) {
      float v1 = b1[s][r], v2 = b2[s][r];
      int   j1 = i1[s][r];
      #pragma unroll
      for (int off = 1; off < 16; off <<= 1) {
        const float o1 = __shfl_xor(v1, off);
        const int   oj = __shfl_xor(j1, off);
        const float o2 = __shfl_xor(v2, off);
        v2 = fminf(fminf(v2, o2), fmaxf(v1, o1));
        const bool tk = (o1 < v1) || (o1 == v1 && oj < j1);
        j1 = tk ? oj : j1;
        v1 = fminf(v1, o1);
      }
      if (l15 == 0) {
        const int rr = kh * N_TOK + rowbase + s * 16 + (g << 2) + r;
        pb1[rr] = v1; pi1[rr] = j1; pb2[rr] = v2;
      }
    }
  }
}

// combine the eight K-eighth partials; final argmin + near-tie flags
__global__ void vq_merge(const float* __restrict__ pb1, const int* __restrict__ pi1,
                         const float* __restrict__ pb2, int* __restrict__ idxf,
                         int* __restrict__ flag, int* __restrict__ cnt) {
  const int gi = blockIdx.x * blockDim.x + threadIdx.x;
  float v1 = pb1[gi], v2 = pb2[gi];
  int   i1 = pi1[gi];
  #pragma unroll
  for (int h = 1; h < 8; ++h) {
    const float o1 = pb1[h * N_TOK + gi];
    const int   oj = pi1[h * N_TOK + gi];
    const float o2 = pb2[h * N_TOK + gi];
    if (o1 < v1 || (o1 == v1 && oj < i1)) {
      v2 = fminf(v1, o2);
      v1 = o1; i1 = oj;
    } else {
      v2 = fminf(v2, o1);
    }
  }
  idxf[gi] = i1;
  if (v2 - v1 < MARGIN) {
    const int p = atomicAdd(cnt, 1);
    if (p < FLAGCAP) flag[p] = gi;
  }
}

// numpy-exact rescan, task-parallel: task = (16-row batch) x (1024-code chunk).
// R11/R13-validated register budget: a[16][4] = 64 accumulators, no spill.
__global__ void vq_rescan2(const float* __restrict__ z,
                           const float* __restrict__ embT,
                           const float* __restrict__ esq,
                           const int* __restrict__ flag,
                           const int* __restrict__ cnt,
                           float* __restrict__ rpv,
                           int* __restrict__ rpi) {
  __shared__ __align__(16) float zT[DIM][16];   // 16KB
  __shared__ float zsq_sh[16];
  __shared__ float rv[4][16];
  __shared__ int   ri[4][16];
  __shared__ int   rown[16];
  int n = *cnt; if (n > FLAGCAP) n = FLAGCAP;
  const int tid = threadIdx.x;
  const int lane = tid & 63, wv = tid >> 6;
  const int nb = (n + 15) >> 4;
  const int ntask = nb * 8;
  for (int task = blockIdx.x; task < ntask; task += gridDim.x) {
    const int bb = task >> 3, cz = task & 7;
    __syncthreads();                 // guard LDS reuse across tasks
    if (tid < 16) rown[tid] = flag[min(bb * 16 + tid, n - 1)];
    __syncthreads();
    #pragma unroll
    for (int rr = 0; rr < 16; ++rr) zT[tid][rr] = z[(size_t)rown[rr] * DIM + tid];
    {
      const int rr = tid >> 4;
      const float s = np_sumsq256(z + (size_t)rown[rr] * DIM, lane);
      if ((tid & 15) == 0) zsq_sh[rr] = s;
    }
    __syncthreads();

    float a[16][4];
    #pragma unroll
    for (int rr = 0; rr < 16; ++rr)
      #pragma unroll
      for (int q = 0; q < 4; ++q) a[rr][q] = 0.f;

    const int c0 = cz * 1024 + tid;
    #pragma unroll 2
    for (int k = 0; k < DIM; ++k) {
      const float* rk = embT + (size_t)k * KC + c0;
      const float e0 = rk[0], e1 = rk[256], e2 = rk[512], e3 = rk[768];
      const f32x4 z0 = *(const f32x4*)&zT[k][0];
      const f32x4 z1 = *(const f32x4*)&zT[k][4];
      const f32x4 z2 = *(const f32x4*)&zT[k][8];
      const f32x4 z3 = *(const f32x4*)&zT[k][12];
      #pragma unroll
      for (int r4 = 0; r4 < 4; ++r4) {
        a[r4][0] = fmaf(z0[r4], e0, a[r4][0]);
        a[r4][1] = fmaf(z0[r4], e1, a[r4][1]);
        a[r4][2] = fmaf(z0[r4], e2, a[r4][2]);
        a[r4][3] = fmaf(z0[r4], e3, a[r4][3]);
        a[4 + r4][0] = fmaf(z1[r4], e0, a[4 + r4][0]);
        a[4 + r4][1] = fmaf(z1[r4], e1, a[4 + r4][1]);
        a[4 + r4][2] = fmaf(z1[r4], e2, a[4 + r4][2]);
        a[4 + r4][3] = fmaf(z1[r4], e3, a[4 + r4][3]);
        a[8 + r4][0] = fmaf(z2[r4], e0, a[8 + r4][0]);
        a[8 + r4][1] = fmaf(z2[r4], e1, a[8 + r4][1]);
        a[8 + r4][2] = fmaf(z2[r4], e2, a[8 + r4][2]);
        a[8 + r4][3] = fmaf(z2[r4], e3, a[8 + r4][3]);
        a[12 + r4][0] = fmaf(z3[r4], e0, a[12 + r4][0]);
        a[12 + r4][1] = fmaf(z3[r4], e1, a[12 + r4][1]);
        a[12 + r4][2] = fmaf(z3[r4], e2, a[12 + r4][2]);
        a[12 + r4][3] = fmaf(z3[r4], e3, a[12 + r4][3]);
      }
    }

    #pragma unroll
    for (int rr = 0; rr < 16; ++rr) {
      float bv = 3.4e38f; int bi = 0x7fffffff;
      #pragma unroll
      for (int q = 0; q < 4; ++q) {
        const int code = cz * 1024 + q * 256 + tid;
        const float D = __fsub_rn(__fadd_rn(zsq_sh[rr], esq[code]), __fmul_rn(2.f, a[rr][q]));
        if (D < bv) { bv = D; bi = code; }   // q ascending -> lowest idx kept
      }
      #pragma unroll
      for (int off = 32; off; off >>= 1) {
        const float ov = __shfl_down(bv, off);
        const int   oi = __shfl_down(bi, off);
        if (ov < bv || (ov == bv && oi < bi)) { bv = ov; bi = oi; }
      }
      if (lane == 0) { rv[wv][rr] = bv; ri[wv][rr] = bi; }
    }
    __syncthreads();
    if (tid < 16) {
      const int fi = bb * 16 + tid;
      if (fi < n) {
        float fv = rv[0][tid]; int fx = ri[0][tid];
        #pragma unroll
        for (int q = 1; q < 4; ++q)
          if (rv[q][tid] < fv || (rv[q][tid] == fv && ri[q][tid] < fx)) { fv = rv[q][tid]; fx = ri[q][tid]; }
        rpv[fi * 8 + cz] = fv; rpi[fi * 8 + cz] = fx;
      }
    }
  }
}

// merge the 8 code-chunk partials per flagged row
__global__ void vq_rmerge(const int* __restrict__ flag, const int* __restrict__ cnt,
                          const float* __restrict__ rpv, const int* __restrict__ rpi,
                          int* __restrict__ idxf) {
  int n = *cnt; if (n > FLAGCAP) n = FLAGCAP;
  const int fi = blockIdx.x * blockDim.x + threadIdx.x;
  if (fi >= n) return;
  float bv = rpv[fi * 8]; int bi = rpi[fi * 8];
  #pragma unroll
  for (int c = 1; c < 8; ++c) {
    const float v = rpv[fi * 8 + c]; const int ix = rpi[fi * 8 + c];
    if (v < bv || (v == bv && ix < bi)) { bv = v; bi = ix; }
  }
  idxf[flag[fi]] = bi;
}

// zq + loss-partials + idx-out + histogram (one wave per row, 4 rows/block)
__global__ void vq_gather(const float* __restrict__ z, const float* __restrict__ emb,
                          const int* __restrict__ idxf, float* __restrict__ out,
                          float* __restrict__ lossp, int* __restrict__ hist) {
  __shared__ float part[4];
  const int tid = threadIdx.x, lane = tid & 63, w = tid >> 6;
  const int row = blockIdx.x * 4 + w;
  const int code = idxf[row];
  const float4 zv = *(const float4*)(z + (size_t)row * DIM + lane * 4);
  const float4 ev = *(const float4*)(emb + (size_t)code * DIM + lane * 4);
  float4 d, o;
  d.x = ev.x - zv.x; d.y = ev.y - zv.y; d.z = ev.z - zv.z; d.w = ev.w - zv.w;
  o.x = zv.x + d.x;  o.y = zv.y + d.y;  o.z = zv.z + d.z;  o.w = zv.w + d.w;
  *(float4*)(out + OUT_ZQ + (size_t)row * DIM + lane * 4) = o;
  float sq = fmaf(d.x, d.x, fmaf(d.y, d.y, fmaf(d.z, d.z, d.w * d.w)));
  #pragma unroll
  for (int off = 32; off; off >>= 1) sq += __shfl_down(sq, off);
  if (lane == 0) {
    part[w] = sq;
    atomicAdd(hist + code, 1);
    out[OUT_IDX + row] = (float)code;
  }
  __syncthreads();
  if (tid == 0) lossp[blockIdx.x] = (part[0] + part[1]) + (part[2] + part[3]);
}

// prefix-scan of histogram + cluster-size output + loss reduction (1 block)
__global__ void vq_prefix(const float* __restrict__ ema_cs, int* __restrict__ hist,
                          int* __restrict__ base, int* __restrict__ cursor,
                          const float* __restrict__ lossp, float* __restrict__ out) {
  __shared__ int ps[256];
  __shared__ float lp[4];
  const int t = threadIdx.x;

  float ls = 0.f;
  #pragma unroll
  for (int j = 0; j < 8; ++j) {
    const float4 v = *(const float4*)(lossp + t * 32 + j * 4);
    ls += (v.x + v.y) + (v.z + v.w);
  }
  #pragma unroll
  for (int off = 32; off; off >>= 1) ls += __shfl_down(ls, off);
  if ((t & 63) == 0) lp[t >> 6] = ls;

  int loc[32]; int s = 0;
  #pragma unroll
  for (int j = 0; j < 32; ++j) { loc[j] = hist[t * 32 + j]; s += loc[j]; }
  ps[t] = s;
  __syncthreads();
  if (t == 0)
    out[OUT_LOSS] = 0.25f * (((lp[0] + lp[1]) + (lp[2] + lp[3])) * (1.f / 8388608.f));
  for (int off = 1; off < 256; off <<= 1) {
    const int v = (t >= off) ? ps[t - off] : 0;
    __syncthreads();
    ps[t] += v;
    __syncthreads();
  }
  int run = ps[t] - s;
  #pragma unroll
  for (int j = 0; j < 32; ++j) {
    const int i = t * 32 + j;
    base[i] = run; cursor[i] = run;
    out[OUT_CS + i] = 0.99f * ema_cs[i] + 0.01f * (float)loc[j];
    run += loc[j];
  }
}

__global__ void vq_slot(const int* __restrict__ idxf, int* __restrict__ cursor,
                        int* __restrict__ rowlist) {
  const int gi = blockIdx.x * blockDim.x + threadIdx.x;
  const int code = idxf[gi];
  const int p = atomicAdd(cursor + code, 1);
  rowlist[p] = gi;
}

// per-code segmented sum + EMA + embeddings finalize
__global__ void vq_embsum(const float* __restrict__ z, const float* __restrict__ ema_sum,
                          const int* __restrict__ rowlist, const int* __restrict__ base,
                          const int* __restrict__ hist, float* __restrict__ out) {
  const int code = blockIdx.x;
  const int lane = threadIdx.x;          // 64 threads = 1 wave
  const int b = base[code], n = hist[code];
  float a0 = 0.f, a1 = 0.f, a2 = 0.f, a3 = 0.f;
  for (int i = 0; i < n; ++i) {
    const float4 v = *(const float4*)(z + (size_t)rowlist[b + i] * DIM + lane * 4);
    a0 += v.x; a1 += v.y; a2 += v.z; a3 += v.w;
  }
  const float4 es = *(const float4*)(ema_sum + (size_t)code * DIM + lane * 4);
  const float s0 = 0.99f * es.x + 0.01f * a0;
  const float s1 = 0.99f * es.y + 0.01f * a1;
  const float s2 = 0.99f * es.z + 0.01f * a2;
  const float s3 = 0.99f * es.w + 0.01f * a3;
  float* sp = out + OUT_SUM + (size_t)code * DIM + lane * 4;   // odd base: scalar stores
  sp[0] = s0; sp[1] = s1; sp[2] = s2; sp[3] = s3;
  const float cs = out[OUT_CS + code] + 1e-5f;
  float* np_ = out + OUT_NEMB + (size_t)code * DIM + lane * 4;
  np_[0] = s0 / cs; np_[1] = s1 / cs; np_[2] = s2 / cs; np_[3] = s3 / cs;
}

extern "C" void kernel_launch(void* const* d_in, const int* in_sizes, int n_in,
                              void* d_out, int out_size, void* d_ws, size_t ws_size,
                              hipStream_t stream) {
  const float* z      = (const float*)d_in[0];
  const float* emb    = (const float*)d_in[1];
  const float* emacs  = (const float*)d_in[2];
  const float* emasum = (const float*)d_in[3];
  float* out = (float*)d_out;
  float* ws  = (float*)d_ws;

  // ws layout (f32 words)
  float* esq     = ws;                        // 8192
  int*   idxf    = (int*)(ws + 8192);         // 32768
  int*   flag    = (int*)(ws + 40960);        // 16384
  int*   cnt     = (int*)(ws + 57344);        // 1 (+pad)
  int*   hist    = (int*)(ws + 57600);        // 8192
  int*   base    = (int*)(ws + 65792);        // 8192
  int*   cursor  = (int*)(ws + 73984);        // 8192
  int*   rowlist = (int*)(ws + 82176);        // 32768
  float* pb1     = ws + 114944;               // 8*32768 (aliased as lossp later)
  int*   pi1     = (int*)(ws + 377088);       // 8*32768
  float* pb2     = ws + 639232;               // 8*32768
  short* esp2    = (short*)(ws + 901376);     // 8192*256 bf16, LDS-image tiled
  float* embT    = ws + 1949952;              // 256*8192 f32 transposed codebook
  float* rpv     = ws + 4047104;              // 16384*8 chunk partial values
  int*   rpi     = (int*)(ws + 4178176);      // 16384*8 chunk partial indices
  float* lossp   = pb1;                       // 8192 partials; pb1 dead by then

  vq_prep<<<KC / 8, 256, 0, stream>>>(emb, esq, esp2, hist, cnt);
  vq_transpose<<<512, 256, 0, stream>>>(emb, embT);

  vq_mfma<<<2048, 256, 0, stream>>>(z, esp2, esq, pb1, pi1, pb2);
  vq_merge<<<N_TOK / 256, 256, 0, stream>>>(pb1, pi1, pb2, idxf, flag, cnt);
  vq_rescan2<<<1024, 256, 0, stream>>>(z, embT, esq, flag, cnt, rpv, rpi);
  vq_rmerge<<<FLAGCAP / 256, 256, 0, stream>>>(flag, cnt, rpv, rpi, idxf);

  vq_gather<<<N_TOK / 4, 256, 0, stream>>>(z, emb, idxf, out, lossp, hist);
  vq_prefix<<<1, 256, 0, stream>>>(emacs, hist, base, cursor, lossp, out);
  vq_slot<<<N_TOK / 256, 256, 0, stream>>>(idxf, cursor, rowlist);
  vq_embsum<<<KC, 64, 0, stream>>>(z, emasum, rowlist, base, hist, out);
}

// Round 20
// 327.741 us; speedup vs baseline: 1.0393x; 1.0393x over previous
//
#include <hip/hip_runtime.h>
#include <hip/hip_bf16.h>
#include <math.h>

#define N_TOK   32768
#define DIM     256
#define KC      8192

// output layout (flat f32, reference tuple order)
#define OUT_ZQ    0
#define OUT_IDX   8388608          // N_TOK*DIM
#define OUT_LOSS  8421376          // +N_TOK
#define OUT_NEMB  8421377          // +1   (NOTE: odd -> scalar stores only)
#define OUT_CS    10518529         // +KC*DIM
#define OUT_SUM   10526721         // +KC  (odd -> scalar stores only)

#define MARGIN  8e-3f              // validated for 1-term phase-1 (R9/R14/R15/R16)
#define FLAGCAP 16384

typedef __attribute__((ext_vector_type(8))) __bf16 bf16x8;
typedef __attribute__((ext_vector_type(4))) float f32x4;

__device__ __forceinline__ void gload16(const void* g, void* l) {
  __builtin_amdgcn_global_load_lds((const __attribute__((address_space(1))) void*)g,
                                   (__attribute__((address_space(3))) void*)l, 16, 0, 0);
}

// ---- numpy pairwise sum-of-squares emulation (validated R3) ----
__device__ __forceinline__ float np_sumsq256(const float* __restrict__ p, int lane) {
  const int l = lane & 15;
  const int h = l >> 3;
  const int j = l & 7;
  const float* a = p + h * 128 + j;
  float x = a[0];
  float r = __fmul_rn(x, x);
  #pragma unroll
  for (int i = 1; i < 16; ++i) {
    x = a[8 * i];
    r = __fadd_rn(r, __fmul_rn(x, x));
  }
  r = __fadd_rn(r, __shfl_down(r, 1));
  r = __fadd_rn(r, __shfl_down(r, 2));
  r = __fadd_rn(r, __shfl_down(r, 4));
  float hi = __shfl(r, (lane & 48) | 8);
  return __fadd_rn(r, hi);
}

// esq (numpy-exact) + esp2 (LDS-image pre-tile) + hist/cnt init (fused)
__global__ void vq_prep(const float* __restrict__ emb, float* __restrict__ esq,
                        short* __restrict__ esp2, int* __restrict__ hist,
                        int* __restrict__ cnt) {
  const int t = threadIdx.x;
  const int code = blockIdx.x * 8 + (t >> 5);
  const int p = t & 31, j = p >> 2, g = p & 3;
  const float* src = emb + (size_t)code * DIM + j * 32 + g * 8;
  const float4 v0 = *(const float4*)src;
  const float4 v1 = *(const float4*)(src + 4);
  const float xf[8] = {v0.x, v0.y, v0.z, v0.w, v1.x, v1.y, v1.z, v1.w};
  bf16x8 hb;
  #pragma unroll
  for (int e = 0; e < 8; ++e) hb[e] = (__bf16)xf[e];
  const int c = code & 15, sub = (code >> 4) & 3, ct = code >> 6;
  const int slot = (g + (c >> 1)) & 3;
  char* dst = (char*)esp2 + (size_t)ct * 32768 + ((sub * 8 + j) << 10) + c * 64 + slot * 16;
  *(bf16x8*)dst = hb;
  if (t < 128) {
    const int code2 = blockIdx.x * 8 + (t >> 4);
    const float s = np_sumsq256(emb + (size_t)code2 * DIM, t & 63);
    if ((t & 15) == 0) esq[code2] = s;
  }
  if (blockIdx.x < 32) hist[blockIdx.x * 256 + t] = 0;
  if (blockIdx.x == 0 && t == 0) cnt[0] = 0;
}

// 64x64-tile transpose: embT[k][code] = emb[code][k]
__global__ void vq_transpose(const float* __restrict__ emb, float* __restrict__ embT) {
  __shared__ float t[64][65];
  const int tid = threadIdx.x;
  const int bc  = blockIdx.x & 127;
  const int bk  = blockIdx.x >> 7;
  const int cc0 = bc << 6, kc0 = bk << 6;
  const int col = tid & 63, qr = tid >> 6;
  #pragma unroll
  for (int i = 0; i < 16; ++i) {
    const int row = i * 4 + qr;
    t[row][col] = emb[(size_t)(cc0 + row) * DIM + kc0 + col];
  }
  __syncthreads();
  #pragma unroll
  for (int i = 0; i < 16; ++i) {
    const int krow = i * 4 + qr;
    embT[(size_t)(kc0 + krow) * KC + cc0 + col] = t[col][krow];
  }
}

// ---- MFMA argmin: R15 config (best measured: 160.8us, occ 35%) ----
// 1024 blocks (256 row-tiles x 4 code-quarters), 32 rows/wave, 64 units,
// 2x16KB dbuf, VGPR ~64 tier.
__launch_bounds__(256, 4)
__global__ void vq_mfma(const float* __restrict__ z,
                        const short* __restrict__ esp,
                        const float* __restrict__ esq,
                        float* __restrict__ pb1,
                        int* __restrict__ pi1,
                        float* __restrict__ pb2) {
  __shared__ __align__(16) char lds[32768];
  const int tid  = threadIdx.x;
  const int lane = tid & 63;
  const int w    = tid >> 6;
  const int l15  = lane & 15;
  const int g    = lane >> 4;
  const int rt   = blockIdx.x >> 2;
  const int kh   = blockIdx.x & 3;
  const int rowbase = rt * 128 + w * 32;
  const int u0 = kh * 64, u1 = u0 + 64;
  const int gx = (g + (l15 >> 1)) & 3;     // conflict-free read slot (R8-verified)
  const char* espb = (const char*)esp;

#define STAGE(U, BUFB)                                                           \
  {                                                                              \
    _Pragma("unroll")                                                            \
    for (int q_ = 0; q_ < 4; ++q_) {                                             \
      const int so_ = (((w << 2) + q_) << 10);                                   \
      gload16(espb + (size_t)(U) * 16384 + so_ + (lane << 4),                    \
              (void*)(lds + (BUFB) + so_));                                      \
    }                                                                            \
  }

  STAGE(u0, 0);

  bf16x8 Ahi[2][8];
  #pragma unroll
  for (int s = 0; s < 2; ++s) {
    const float* zr = z + (size_t)(rowbase + s * 16 + l15) * DIM + g * 8;
    #pragma unroll
    for (int c = 0; c < 8; ++c) {
      const float4 v0 = *(const float4*)(zr + c * 32);
      const float4 v1 = *(const float4*)(zr + c * 32 + 4);
      const float xf[8] = {v0.x, v0.y, v0.z, v0.w, v1.x, v1.y, v1.z, v1.w};
      #pragma unroll
      for (int e = 0; e < 8; ++e) Ahi[s][c][e] = (__bf16)xf[e];
    }
  }

  __syncthreads();

  float b1[2][4], b2[2][4];
  int   i1[2][4];
  #pragma unroll
  for (int s = 0; s < 2; ++s)
    #pragma unroll
    for (int r = 0; r < 4; ++r) { b1[s][r] = 3.4e38f; b2[s][r] = 3.4e38f; i1[s][r] = 0x7fffffff; }

  int bp = 0;
  for (int u = u0; u < u1; ++u) {
    if (u + 1 < u1) STAGE(u + 1, (bp ^ 1) << 14);

    const float eq0 = esq[(u << 5) + l15];
    const float eq1 = esq[(u << 5) + 16 + l15];

    f32x4 acc00 = (f32x4){0.f, 0.f, 0.f, 0.f};
    f32x4 acc01 = (f32x4){0.f, 0.f, 0.f, 0.f};
    f32x4 acc10 = (f32x4){0.f, 0.f, 0.f, 0.f};
    f32x4 acc11 = (f32x4){0.f, 0.f, 0.f, 0.f};

    {
      const char* base = lds + (bp << 14);
      #pragma unroll
      for (int j_ = 0; j_ < 8; ++j_) {
        const char* bq_ = base + (j_ << 10) + (l15 << 6) + (gx << 4);
        const bf16x8 bF0 = *(const bf16x8*)(bq_);
        const bf16x8 bF1 = *(const bf16x8*)(bq_ + 8192);
        acc00 = __builtin_amdgcn_mfma_f32_16x16x32_bf16(Ahi[0][j_], bF0, acc00, 0, 0, 0);
        acc01 = __builtin_amdgcn_mfma_f32_16x16x32_bf16(Ahi[0][j_], bF1, acc01, 0, 0, 0);
        acc10 = __builtin_amdgcn_mfma_f32_16x16x32_bf16(Ahi[1][j_], bF0, acc10, 0, 0, 0);
        acc11 = __builtin_amdgcn_mfma_f32_16x16x32_bf16(Ahi[1][j_], bF1, acc11, 0, 0, 0);
      }
    }

    const int code0 = (u << 5) + l15;
    const int code1 = code0 + 16;
    #pragma unroll
    for (int r = 0; r < 4; ++r) {
      const float sc = fmaf(-2.f, acc00[r], eq0);
      const bool lt = sc < b1[0][r];
      b2[0][r] = fminf(b2[0][r], fmaxf(sc, b1[0][r]));
      i1[0][r] = lt ? code0 : i1[0][r];
      b1[0][r] = fminf(b1[0][r], sc);
    }
    #pragma unroll
    for (int r = 0; r < 4; ++r) {
      const float sc = fmaf(-2.f, acc01[r], eq1);
      const bool lt = sc < b1[0][r];
      b2[0][r] = fminf(b2[0][r], fmaxf(sc, b1[0][r]));
      i1[0][r] = lt ? code1 : i1[0][r];
      b1[0][r] = fminf(b1[0][r], sc);
    }
    #pragma unroll
    for (int r = 0; r < 4; ++r) {
      const float sc = fmaf(-2.f, acc10[r], eq0);
      const bool lt = sc < b1[1][r];
      b2[1][r] = fminf(b2[1][r], fmaxf(sc, b1[1][r]));
      i1[1][r] = lt ? code0 : i1[1][r];
      b1[1][r] = fminf(b1[1][r], sc);
    }
    #pragma unroll
    for (int r = 0; r < 4; ++r) {
      const float sc = fmaf(-2.f, acc11[r], eq1);
      const bool lt = sc < b1[1][r];
      b2[1][r] = fminf(b2[1][r], fmaxf(sc, b1[1][r]));
      i1[1][r] = lt ? code1 : i1[1][r];
      b1[1][r] = fminf(b1[1][r], sc);
    }
    __syncthreads();
    bp ^= 1;
  }

  #pragma unroll
  for (int s = 0; s < 2; ++s) {
    #pragma unroll
    for (int r = 0; r < 4; ++r) {
      float v1 = b1[s][r], v2 = b2[s][r];
      int   j1 = i1[s][r];
      #pragma unroll
      for (int off = 1; off < 16; off <<= 1) {
        const float o1 = __shfl_xor(v1, off);
        const int   oj = __shfl_xor(j1, off);
        const float o2 = __shfl_xor(v2, off);
        v2 = fminf(fminf(v2, o2), fmaxf(v1, o1));
        const bool tk = (o1 < v1) || (o1 == v1 && oj < j1);
        j1 = tk ? oj : j1;
        v1 = fminf(v1, o1);
      }
      if (l15 == 0) {
        const int rr = kh * N_TOK + rowbase + s * 16 + (g << 2) + r;
        pb1[rr] = v1; pi1[rr] = j1; pb2[rr] = v2;
      }
    }
  }
}

// combine the four K-quarter partials; final argmin + near-tie flags
__global__ void vq_merge(const float* __restrict__ pb1, const int* __restrict__ pi1,
                         const float* __restrict__ pb2, int* __restrict__ idxf,
                         int* __restrict__ flag, int* __restrict__ cnt) {
  const int gi = blockIdx.x * blockDim.x + threadIdx.x;
  float v1 = pb1[gi], v2 = pb2[gi];
  int   i1 = pi1[gi];
  #pragma unroll
  for (int h = 1; h < 4; ++h) {
    const float o1 = pb1[h * N_TOK + gi];
    const int   oj = pi1[h * N_TOK + gi];
    const float o2 = pb2[h * N_TOK + gi];
    if (o1 < v1 || (o1 == v1 && oj < i1)) {
      v2 = fminf(v1, o2);
      v1 = o1; i1 = oj;
    } else {
      v2 = fminf(v2, o1);
    }
  }
  idxf[gi] = i1;
  if (v2 - v1 < MARGIN) {
    const int p = atomicAdd(cnt, 1);
    if (p < FLAGCAP) flag[p] = gi;
  }
}

// numpy-exact rescan, task-parallel: task = (16-row batch) x (1024-code chunk).
__global__ void vq_rescan2(const float* __restrict__ z,
                           const float* __restrict__ embT,
                           const float* __restrict__ esq,
                           const int* __restrict__ flag,
                           const int* __restrict__ cnt,
                           float* __restrict__ rpv,
                           int* __restrict__ rpi) {
  __shared__ __align__(16) float zT[DIM][16];
  __shared__ float zsq_sh[16];
  __shared__ float rv[4][16];
  __shared__ int   ri[4][16];
  __shared__ int   rown[16];
  int n = *cnt; if (n > FLAGCAP) n = FLAGCAP;
  const int tid = threadIdx.x;
  const int lane = tid & 63, wv = tid >> 6;
  const int nb = (n + 15) >> 4;
  const int ntask = nb * 8;
  for (int task = blockIdx.x; task < ntask; task += gridDim.x) {
    const int bb = task >> 3, cz = task & 7;
    __syncthreads();
    if (tid < 16) rown[tid] = flag[min(bb * 16 + tid, n - 1)];
    __syncthreads();
    #pragma unroll
    for (int rr = 0; rr < 16; ++rr) zT[tid][rr] = z[(size_t)rown[rr] * DIM + tid];
    {
      const int rr = tid >> 4;
      const float s = np_sumsq256(z + (size_t)rown[rr] * DIM, lane);
      if ((tid & 15) == 0) zsq_sh[rr] = s;
    }
    __syncthreads();

    float a[16][4];
    #pragma unroll
    for (int rr = 0; rr < 16; ++rr)
      #pragma unroll
      for (int q = 0; q < 4; ++q) a[rr][q] = 0.f;

    const int c0 = cz * 1024 + tid;
    #pragma unroll 2
    for (int k = 0; k < DIM; ++k) {
      const float* rk = embT + (size_t)k * KC + c0;
      const float e0 = rk[0], e1 = rk[256], e2 = rk[512], e3 = rk[768];
      const f32x4 z0 = *(const f32x4*)&zT[k][0];
      const f32x4 z1 = *(const f32x4*)&zT[k][4];
      const f32x4 z2 = *(const f32x4*)&zT[k][8];
      const f32x4 z3 = *(const f32x4*)&zT[k][12];
      #pragma unroll
      for (int r4 = 0; r4 < 4; ++r4) {
        a[r4][0] = fmaf(z0[r4], e0, a[r4][0]);
        a[r4][1] = fmaf(z0[r4], e1, a[r4][1]);
        a[r4][2] = fmaf(z0[r4], e2, a[r4][2]);
        a[r4][3] = fmaf(z0[r4], e3, a[r4][3]);
        a[4 + r4][0] = fmaf(z1[r4], e0, a[4 + r4][0]);
        a[4 + r4][1] = fmaf(z1[r4], e1, a[4 + r4][1]);
        a[4 + r4][2] = fmaf(z1[r4], e2, a[4 + r4][2]);
        a[4 + r4][3] = fmaf(z1[r4], e3, a[4 + r4][3]);
        a[8 + r4][0] = fmaf(z2[r4], e0, a[8 + r4][0]);
        a[8 + r4][1] = fmaf(z2[r4], e1, a[8 + r4][1]);
        a[8 + r4][2] = fmaf(z2[r4], e2, a[8 + r4][2]);
        a[8 + r4][3] = fmaf(z2[r4], e3, a[8 + r4][3]);
        a[12 + r4][0] = fmaf(z3[r4], e0, a[12 + r4][0]);
        a[12 + r4][1] = fmaf(z3[r4], e1, a[12 + r4][1]);
        a[12 + r4][2] = fmaf(z3[r4], e2, a[12 + r4][2]);
        a[12 + r4][3] = fmaf(z3[r4], e3, a[12 + r4][3]);
      }
    }

    #pragma unroll
    for (int rr = 0; rr < 16; ++rr) {
      float bv = 3.4e38f; int bi = 0x7fffffff;
      #pragma unroll
      for (int q = 0; q < 4; ++q) {
        const int code = cz * 1024 + q * 256 + tid;
        const float D = __fsub_rn(__fadd_rn(zsq_sh[rr], esq[code]), __fmul_rn(2.f, a[rr][q]));
        if (D < bv) { bv = D; bi = code; }
      }
      #pragma unroll
      for (int off = 32; off; off >>= 1) {
        const float ov = __shfl_down(bv, off);
        const int   oi = __shfl_down(bi, off);
        if (ov < bv || (ov == bv && oi < bi)) { bv = ov; bi = oi; }
      }
      if (lane == 0) { rv[wv][rr] = bv; ri[wv][rr] = bi; }
    }
    __syncthreads();
    if (tid < 16) {
      const int fi = bb * 16 + tid;
      if (fi < n) {
        float fv = rv[0][tid]; int fx = ri[0][tid];
        #pragma unroll
        for (int q = 1; q < 4; ++q)
          if (rv[q][tid] < fv || (rv[q][tid] == fv && ri[q][tid] < fx)) { fv = rv[q][tid]; fx = ri[q][tid]; }
        rpv[fi * 8 + cz] = fv; rpi[fi * 8 + cz] = fx;
      }
    }
  }
}

// merge the 8 code-chunk partials per flagged row
__global__ void vq_rmerge(const int* __restrict__ flag, const int* __restrict__ cnt,
                          const float* __restrict__ rpv, const int* __restrict__ rpi,
                          int* __restrict__ idxf) {
  int n = *cnt; if (n > FLAGCAP) n = FLAGCAP;
  const int fi = blockIdx.x * blockDim.x + threadIdx.x;
  if (fi >= n) return;
  float bv = rpv[fi * 8]; int bi = rpi[fi * 8];
  #pragma unroll
  for (int c = 1; c < 8; ++c) {
    const float v = rpv[fi * 8 + c]; const int ix = rpi[fi * 8 + c];
    if (v < bv || (v == bv && ix < bi)) { bv = v; bi = ix; }
  }
  idxf[flag[fi]] = bi;
}

// histogram + idx output (gather's bookkeeping, no data movement)
__global__ void vq_hist(const int* __restrict__ idxf, int* __restrict__ hist,
                        float* __restrict__ out) {
  const int gi = blockIdx.x * blockDim.x + threadIdx.x;
  const int code = idxf[gi];
  atomicAdd(hist + code, 1);
  out[OUT_IDX + gi] = (float)code;
}

// prefix-scan of histogram + cluster-size output (1 block)
__global__ void vq_prefix(const float* __restrict__ ema_cs, int* __restrict__ hist,
                          int* __restrict__ base, int* __restrict__ cursor,
                          float* __restrict__ out) {
  __shared__ int ps[256];
  const int t = threadIdx.x;
  int loc[32]; int s = 0;
  #pragma unroll
  for (int j = 0; j < 32; ++j) { loc[j] = hist[t * 32 + j]; s += loc[j]; }
  ps[t] = s;
  __syncthreads();
  for (int off = 1; off < 256; off <<= 1) {
    const int v = (t >= off) ? ps[t - off] : 0;
    __syncthreads();
    ps[t] += v;
    __syncthreads();
  }
  int run = ps[t] - s;
  #pragma unroll
  for (int j = 0; j < 32; ++j) {
    const int i = t * 32 + j;
    base[i] = run; cursor[i] = run;
    out[OUT_CS + i] = 0.99f * ema_cs[i] + 0.01f * (float)loc[j];
    run += loc[j];
  }
}

__global__ void vq_slot(const int* __restrict__ idxf, int* __restrict__ cursor,
                        int* __restrict__ rowlist) {
  const int gi = blockIdx.x * blockDim.x + threadIdx.x;
  const int code = idxf[gi];
  const int p = atomicAdd(cursor + code, 1);
  rowlist[p] = gi;
}

// FUSED: per-code zq-write (zq = emb[code]) + loss partial + segmented z-sum
// + EMA + embeddings finalize. One wave per code.
__global__ void vq_embsum(const float* __restrict__ z, const float* __restrict__ emb,
                          const float* __restrict__ ema_sum,
                          const int* __restrict__ rowlist, const int* __restrict__ base,
                          const int* __restrict__ hist, float* __restrict__ out,
                          float* __restrict__ lossp) {
  const int code = blockIdx.x;
  const int lane = threadIdx.x;          // 64 threads = 1 wave
  const int b = base[code], n = hist[code];
  const float4 ev = *(const float4*)(emb + (size_t)code * DIM + lane * 4);
  float a0 = 0.f, a1 = 0.f, a2 = 0.f, a3 = 0.f, ls = 0.f;
  for (int i = 0; i < n; ++i) {
    const int row = rowlist[b + i];
    const float4 v = *(const float4*)(z + (size_t)row * DIM + lane * 4);
    a0 += v.x; a1 += v.y; a2 += v.z; a3 += v.w;
    const float d0 = ev.x - v.x, d1 = ev.y - v.y, d2 = ev.z - v.z, d3 = ev.w - v.w;
    ls = fmaf(d0, d0, fmaf(d1, d1, fmaf(d2, d2, fmaf(d3, d3, ls))));
    *(float4*)(out + OUT_ZQ + (size_t)row * DIM + lane * 4) = ev;  // z + (e-z) = e
  }
  #pragma unroll
  for (int off = 32; off; off >>= 1) ls += __shfl_down(ls, off);
  if (lane == 0) lossp[code] = ls;
  const float4 es = *(const float4*)(ema_sum + (size_t)code * DIM + lane * 4);
  const float s0 = 0.99f * es.x + 0.01f * a0;
  const float s1 = 0.99f * es.y + 0.01f * a1;
  const float s2 = 0.99f * es.z + 0.01f * a2;
  const float s3 = 0.99f * es.w + 0.01f * a3;
  float* sp = out + OUT_SUM + (size_t)code * DIM + lane * 4;   // odd base: scalar stores
  sp[0] = s0; sp[1] = s1; sp[2] = s2; sp[3] = s3;
  const float cs = out[OUT_CS + code] + 1e-5f;
  float* np_ = out + OUT_NEMB + (size_t)code * DIM + lane * 4;
  np_[0] = s0 / cs; np_[1] = s1 / cs; np_[2] = s2 / cs; np_[3] = s3 / cs;
}

// reduce 8192 per-code loss partials -> scalar (1 block)
__global__ void vq_lossred(const float* __restrict__ lossp, float* __restrict__ out) {
  __shared__ float lp[4];
  const int t = threadIdx.x;
  float ls = 0.f;
  #pragma unroll
  for (int j = 0; j < 8; ++j) {
    const float4 v = *(const float4*)(lossp + t * 32 + j * 4);
    ls += (v.x + v.y) + (v.z + v.w);
  }
  #pragma unroll
  for (int off = 32; off; off >>= 1) ls += __shfl_down(ls, off);
  if ((t & 63) == 0) lp[t >> 6] = ls;
  __syncthreads();
  if (t == 0)
    out[OUT_LOSS] = 0.25f * (((lp[0] + lp[1]) + (lp[2] + lp[3])) * (1.f / 8388608.f));
}

extern "C" void kernel_launch(void* const* d_in, const int* in_sizes, int n_in,
                              void* d_out, int out_size, void* d_ws, size_t ws_size,
                              hipStream_t stream) {
  const float* z      = (const float*)d_in[0];
  const float* emb    = (const float*)d_in[1];
  const float* emacs  = (const float*)d_in[2];
  const float* emasum = (const float*)d_in[3];
  float* out = (float*)d_out;
  float* ws  = (float*)d_ws;

  // ws layout (f32 words)
  float* esq     = ws;                        // 8192
  int*   idxf    = (int*)(ws + 8192);         // 32768
  int*   flag    = (int*)(ws + 40960);        // 16384
  int*   cnt     = (int*)(ws + 57344);        // 1 (+pad)
  int*   hist    = (int*)(ws + 57600);        // 8192
  int*   base    = (int*)(ws + 65792);        // 8192
  int*   cursor  = (int*)(ws + 73984);        // 8192
  int*   rowlist = (int*)(ws + 82176);        // 32768
  float* pb1     = ws + 114944;               // 4*32768 (lossp aliases after merge)
  int*   pi1     = (int*)(ws + 246016);       // 4*32768
  float* pb2     = ws + 377088;               // 4*32768
  short* esp2    = (short*)(ws + 508160);     // 8192*256 bf16, LDS-image tiled
  float* embT    = ws + 1556736;              // 256*8192 f32 transposed codebook
  float* rpv     = ws + 3653888;              // 16384*8 chunk partial values
  int*   rpi     = (int*)(ws + 3784960);      // 16384*8 chunk partial indices
  float* lossp   = pb1;                       // 8192 per-code loss partials

  vq_prep<<<KC / 8, 256, 0, stream>>>(emb, esq, esp2, hist, cnt);
  vq_transpose<<<512, 256, 0, stream>>>(emb, embT);

  vq_mfma<<<1024, 256, 0, stream>>>(z, esp2, esq, pb1, pi1, pb2);
  vq_merge<<<N_TOK / 256, 256, 0, stream>>>(pb1, pi1, pb2, idxf, flag, cnt);
  vq_rescan2<<<1024, 256, 0, stream>>>(z, embT, esq, flag, cnt, rpv, rpi);
  vq_rmerge<<<FLAGCAP / 256, 256, 0, stream>>>(flag, cnt, rpv, rpi, idxf);

  vq_hist<<<N_TOK / 256, 256, 0, stream>>>(idxf, hist, out);
  vq_prefix<<<1, 256, 0, stream>>>(emacs, hist, base, cursor, out);
  vq_slot<<<N_TOK / 256, 256, 0, stream>>>(idxf, cursor, rowlist);
  vq_embsum<<<KC, 64, 0, stream>>>(z, emb, emasum, rowlist, base, hist, out, lossp);
  vq_lossred<<<1, 256, 0, stream>>>(lossp, out);
}

// Round 21
// 322.105 us; speedup vs baseline: 1.0574x; 1.0175x over previous
//
#include <hip/hip_runtime.h>
#include <hip/hip_bf16.h>
#include <math.h>

#define N_TOK   32768
#define DIM     256
#define KC      8192

// output layout (flat f32, reference tuple order)
#define OUT_ZQ    0
#define OUT_IDX   8388608          // N_TOK*DIM
#define OUT_LOSS  8421376          // +N_TOK
#define OUT_NEMB  8421377          // +1   (NOTE: odd -> scalar stores only)
#define OUT_CS    10518529         // +KC*DIM
#define OUT_SUM   10526721         // +KC  (odd -> scalar stores only)

#define MARGIN  8e-3f              // validated for 1-term phase-1 (R9/R14/R15/R16/R20)
#define FLAGCAP 16384

typedef __attribute__((ext_vector_type(8))) __bf16 bf16x8;
typedef __attribute__((ext_vector_type(4))) float f32x4;

__device__ __forceinline__ void gload16(const void* g, void* l) {
  __builtin_amdgcn_global_load_lds((const __attribute__((address_space(1))) void*)g,
                                   (__attribute__((address_space(3))) void*)l, 16, 0, 0);
}

// ---- numpy pairwise sum-of-squares emulation (validated R3) ----
__device__ __forceinline__ float np_sumsq256(const float* __restrict__ p, int lane) {
  const int l = lane & 15;
  const int h = l >> 3;
  const int j = l & 7;
  const float* a = p + h * 128 + j;
  float x = a[0];
  float r = __fmul_rn(x, x);
  #pragma unroll
  for (int i = 1; i < 16; ++i) {
    x = a[8 * i];
    r = __fadd_rn(r, __fmul_rn(x, x));
  }
  r = __fadd_rn(r, __shfl_down(r, 1));
  r = __fadd_rn(r, __shfl_down(r, 2));
  r = __fadd_rn(r, __shfl_down(r, 4));
  float hi = __shfl(r, (lane & 48) | 8);
  return __fadd_rn(r, hi);
}

// FUSED preprocessing: blocks 0..1023 = esq (numpy-exact) + esp2 (LDS-image
// pre-tile) + hist/cnt init; blocks 1024..1535 = embT transpose.
__global__ void vq_prep(const float* __restrict__ emb, float* __restrict__ esq,
                        short* __restrict__ esp2, float* __restrict__ embT,
                        int* __restrict__ hist, int* __restrict__ cnt) {
  __shared__ float tt[64][65];
  const int t = threadIdx.x;
  if (blockIdx.x < 1024) {
    const int code = blockIdx.x * 8 + (t >> 5);
    const int p = t & 31, j = p >> 2, g = p & 3;
    const float* src = emb + (size_t)code * DIM + j * 32 + g * 8;
    const float4 v0 = *(const float4*)src;
    const float4 v1 = *(const float4*)(src + 4);
    const float xf[8] = {v0.x, v0.y, v0.z, v0.w, v1.x, v1.y, v1.z, v1.w};
    bf16x8 hb;
    #pragma unroll
    for (int e = 0; e < 8; ++e) hb[e] = (__bf16)xf[e];
    const int c = code & 15, sub = (code >> 4) & 3, ct = code >> 6;
    const int slot = (g + (c >> 1)) & 3;
    char* dst = (char*)esp2 + (size_t)ct * 32768 + ((sub * 8 + j) << 10) + c * 64 + slot * 16;
    *(bf16x8*)dst = hb;
    if (t < 128) {
      const int code2 = blockIdx.x * 8 + (t >> 4);
      const float s = np_sumsq256(emb + (size_t)code2 * DIM, t & 63);
      if ((t & 15) == 0) esq[code2] = s;
    }
    if (blockIdx.x < 32) hist[blockIdx.x * 256 + t] = 0;
    if (blockIdx.x == 0 && t == 0) cnt[0] = 0;
  } else {
    const int bid = blockIdx.x - 1024;
    const int bc  = bid & 127;
    const int bk  = bid >> 7;
    const int cc0 = bc << 6, kc0 = bk << 6;
    const int col = t & 63, qr = t >> 6;
    #pragma unroll
    for (int i = 0; i < 16; ++i) {
      const int row = i * 4 + qr;
      tt[row][col] = emb[(size_t)(cc0 + row) * DIM + kc0 + col];
    }
    __syncthreads();
    #pragma unroll
    for (int i = 0; i < 16; ++i) {
      const int krow = i * 4 + qr;
      embT[(size_t)(kc0 + krow) * KC + cc0 + col] = tt[col][krow];
    }
  }
}

// ---- MFMA argmin: R15 config (best measured: 160.8us, occ 35%) ----
// 1024 blocks (256 row-tiles x 4 code-quarters), 32 rows/wave, 64 units,
// 2x16KB dbuf, VGPR ~64 tier.
__launch_bounds__(256, 4)
__global__ void vq_mfma(const float* __restrict__ z,
                        const short* __restrict__ esp,
                        const float* __restrict__ esq,
                        float* __restrict__ pb1,
                        int* __restrict__ pi1,
                        float* __restrict__ pb2) {
  __shared__ __align__(16) char lds[32768];
  const int tid  = threadIdx.x;
  const int lane = tid & 63;
  const int w    = tid >> 6;
  const int l15  = lane & 15;
  const int g    = lane >> 4;
  const int rt   = blockIdx.x >> 2;
  const int kh   = blockIdx.x & 3;
  const int rowbase = rt * 128 + w * 32;
  const int u0 = kh * 64, u1 = u0 + 64;
  const int gx = (g + (l15 >> 1)) & 3;     // conflict-free read slot (R8-verified)
  const char* espb = (const char*)esp;

#define STAGE(U, BUFB)                                                           \
  {                                                                              \
    _Pragma("unroll")                                                            \
    for (int q_ = 0; q_ < 4; ++q_) {                                             \
      const int so_ = (((w << 2) + q_) << 10);                                   \
      gload16(espb + (size_t)(U) * 16384 + so_ + (lane << 4),                    \
              (void*)(lds + (BUFB) + so_));                                      \
    }                                                                            \
  }

  STAGE(u0, 0);

  bf16x8 Ahi[2][8];
  #pragma unroll
  for (int s = 0; s < 2; ++s) {
    const float* zr = z + (size_t)(rowbase + s * 16 + l15) * DIM + g * 8;
    #pragma unroll
    for (int c = 0; c < 8; ++c) {
      const float4 v0 = *(const float4*)(zr + c * 32);
      const float4 v1 = *(const float4*)(zr + c * 32 + 4);
      const float xf[8] = {v0.x, v0.y, v0.z, v0.w, v1.x, v1.y, v1.z, v1.w};
      #pragma unroll
      for (int e = 0; e < 8; ++e) Ahi[s][c][e] = (__bf16)xf[e];
    }
  }

  __syncthreads();

  float b1[2][4], b2[2][4];
  int   i1[2][4];
  #pragma unroll
  for (int s = 0; s < 2; ++s)
    #pragma unroll
    for (int r = 0; r < 4; ++r) { b1[s][r] = 3.4e38f; b2[s][r] = 3.4e38f; i1[s][r] = 0x7fffffff; }

  int bp = 0;
  for (int u = u0; u < u1; ++u) {
    if (u + 1 < u1) STAGE(u + 1, (bp ^ 1) << 14);

    const float eq0 = esq[(u << 5) + l15];
    const float eq1 = esq[(u << 5) + 16 + l15];

    f32x4 acc00 = (f32x4){0.f, 0.f, 0.f, 0.f};
    f32x4 acc01 = (f32x4){0.f, 0.f, 0.f, 0.f};
    f32x4 acc10 = (f32x4){0.f, 0.f, 0.f, 0.f};
    f32x4 acc11 = (f32x4){0.f, 0.f, 0.f, 0.f};

    {
      const char* base = lds + (bp << 14);
      #pragma unroll
      for (int j_ = 0; j_ < 8; ++j_) {
        const char* bq_ = base + (j_ << 10) + (l15 << 6) + (gx << 4);
        const bf16x8 bF0 = *(const bf16x8*)(bq_);
        const bf16x8 bF1 = *(const bf16x8*)(bq_ + 8192);
        acc00 = __builtin_amdgcn_mfma_f32_16x16x32_bf16(Ahi[0][j_], bF0, acc00, 0, 0, 0);
        acc01 = __builtin_amdgcn_mfma_f32_16x16x32_bf16(Ahi[0][j_], bF1, acc01, 0, 0, 0);
        acc10 = __builtin_amdgcn_mfma_f32_16x16x32_bf16(Ahi[1][j_], bF0, acc10, 0, 0, 0);
        acc11 = __builtin_amdgcn_mfma_f32_16x16x32_bf16(Ahi[1][j_], bF1, acc11, 0, 0, 0);
      }
    }

    const int code0 = (u << 5) + l15;
    const int code1 = code0 + 16;
    #pragma unroll
    for (int r = 0; r < 4; ++r) {
      const float sc = fmaf(-2.f, acc00[r], eq0);
      const bool lt = sc < b1[0][r];
      b2[0][r] = fminf(b2[0][r], fmaxf(sc, b1[0][r]));
      i1[0][r] = lt ? code0 : i1[0][r];
      b1[0][r] = fminf(b1[0][r], sc);
    }
    #pragma unroll
    for (int r = 0; r < 4; ++r) {
      const float sc = fmaf(-2.f, acc01[r], eq1);
      const bool lt = sc < b1[0][r];
      b2[0][r] = fminf(b2[0][r], fmaxf(sc, b1[0][r]));
      i1[0][r] = lt ? code1 : i1[0][r];
      b1[0][r] = fminf(b1[0][r], sc);
    }
    #pragma unroll
    for (int r = 0; r < 4; ++r) {
      const float sc = fmaf(-2.f, acc10[r], eq0);
      const bool lt = sc < b1[1][r];
      b2[1][r] = fminf(b2[1][r], fmaxf(sc, b1[1][r]));
      i1[1][r] = lt ? code0 : i1[1][r];
      b1[1][r] = fminf(b1[1][r], sc);
    }
    #pragma unroll
    for (int r = 0; r < 4; ++r) {
      const float sc = fmaf(-2.f, acc11[r], eq1);
      const bool lt = sc < b1[1][r];
      b2[1][r] = fminf(b2[1][r], fmaxf(sc, b1[1][r]));
      i1[1][r] = lt ? code1 : i1[1][r];
      b1[1][r] = fminf(b1[1][r], sc);
    }
    __syncthreads();
    bp ^= 1;
  }

  #pragma unroll
  for (int s = 0; s < 2; ++s) {
    #pragma unroll
    for (int r = 0; r < 4; ++r) {
      float v1 = b1[s][r], v2 = b2[s][r];
      int   j1 = i1[s][r];
      #pragma unroll
      for (int off = 1; off < 16; off <<= 1) {
        const float o1 = __shfl_xor(v1, off);
        const int   oj = __shfl_xor(j1, off);
        const float o2 = __shfl_xor(v2, off);
        v2 = fminf(fminf(v2, o2), fmaxf(v1, o1));
        const bool tk = (o1 < v1) || (o1 == v1 && oj < j1);
        j1 = tk ? oj : j1;
        v1 = fminf(v1, o1);
      }
      if (l15 == 0) {
        const int rr = kh * N_TOK + rowbase + s * 16 + (g << 2) + r;
        pb1[rr] = v1; pi1[rr] = j1; pb2[rr] = v2;
      }
    }
  }
}

// combine the four K-quarter partials; final argmin + near-tie flags.
// FUSED: unflagged rows write hist + OUT_IDX here (flagged handled by rmerge).
__global__ void vq_merge(const float* __restrict__ pb1, const int* __restrict__ pi1,
                         const float* __restrict__ pb2, int* __restrict__ idxf,
                         int* __restrict__ flag, int* __restrict__ cnt,
                         int* __restrict__ hist, float* __restrict__ out) {
  const int gi = blockIdx.x * blockDim.x + threadIdx.x;
  float v1 = pb1[gi], v2 = pb2[gi];
  int   i1 = pi1[gi];
  #pragma unroll
  for (int h = 1; h < 4; ++h) {
    const float o1 = pb1[h * N_TOK + gi];
    const int   oj = pi1[h * N_TOK + gi];
    const float o2 = pb2[h * N_TOK + gi];
    if (o1 < v1 || (o1 == v1 && oj < i1)) {
      v2 = fminf(v1, o2);
      v1 = o1; i1 = oj;
    } else {
      v2 = fminf(v2, o1);
    }
  }
  idxf[gi] = i1;
  bool deferred = false;
  if (v2 - v1 < MARGIN) {
    const int p = atomicAdd(cnt, 1);
    if (p < FLAGCAP) { flag[p] = gi; deferred = true; }
  }
  if (!deferred) {
    atomicAdd(hist + i1, 1);
    out[OUT_IDX + gi] = (float)i1;
  }
}

// numpy-exact rescan, task-parallel: task = (16-row batch) x (1024-code chunk).
__global__ void vq_rescan2(const float* __restrict__ z,
                           const float* __restrict__ embT,
                           const float* __restrict__ esq,
                           const int* __restrict__ flag,
                           const int* __restrict__ cnt,
                           float* __restrict__ rpv,
                           int* __restrict__ rpi) {
  __shared__ __align__(16) float zT[DIM][16];
  __shared__ float zsq_sh[16];
  __shared__ float rv[4][16];
  __shared__ int   ri[4][16];
  __shared__ int   rown[16];
  int n = *cnt; if (n > FLAGCAP) n = FLAGCAP;
  const int tid = threadIdx.x;
  const int lane = tid & 63, wv = tid >> 6;
  const int nb = (n + 15) >> 4;
  const int ntask = nb * 8;
  for (int task = blockIdx.x; task < ntask; task += gridDim.x) {
    const int bb = task >> 3, cz = task & 7;
    __syncthreads();
    if (tid < 16) rown[tid] = flag[min(bb * 16 + tid, n - 1)];
    __syncthreads();
    #pragma unroll
    for (int rr = 0; rr < 16; ++rr) zT[tid][rr] = z[(size_t)rown[rr] * DIM + tid];
    {
      const int rr = tid >> 4;
      const float s = np_sumsq256(z + (size_t)rown[rr] * DIM, lane);
      if ((tid & 15) == 0) zsq_sh[rr] = s;
    }
    __syncthreads();

    float a[16][4];
    #pragma unroll
    for (int rr = 0; rr < 16; ++rr)
      #pragma unroll
      for (int q = 0; q < 4; ++q) a[rr][q] = 0.f;

    const int c0 = cz * 1024 + tid;
    #pragma unroll 2
    for (int k = 0; k < DIM; ++k) {
      const float* rk = embT + (size_t)k * KC + c0;
      const float e0 = rk[0], e1 = rk[256], e2 = rk[512], e3 = rk[768];
      const f32x4 z0 = *(const f32x4*)&zT[k][0];
      const f32x4 z1 = *(const f32x4*)&zT[k][4];
      const f32x4 z2 = *(const f32x4*)&zT[k][8];
      const f32x4 z3 = *(const f32x4*)&zT[k][12];
      #pragma unroll
      for (int r4 = 0; r4 < 4; ++r4) {
        a[r4][0] = fmaf(z0[r4], e0, a[r4][0]);
        a[r4][1] = fmaf(z0[r4], e1, a[r4][1]);
        a[r4][2] = fmaf(z0[r4], e2, a[r4][2]);
        a[r4][3] = fmaf(z0[r4], e3, a[r4][3]);
        a[4 + r4][0] = fmaf(z1[r4], e0, a[4 + r4][0]);
        a[4 + r4][1] = fmaf(z1[r4], e1, a[4 + r4][1]);
        a[4 + r4][2] = fmaf(z1[r4], e2, a[4 + r4][2]);
        a[4 + r4][3] = fmaf(z1[r4], e3, a[4 + r4][3]);
        a[8 + r4][0] = fmaf(z2[r4], e0, a[8 + r4][0]);
        a[8 + r4][1] = fmaf(z2[r4], e1, a[8 + r4][1]);
        a[8 + r4][2] = fmaf(z2[r4], e2, a[8 + r4][2]);
        a[8 + r4][3] = fmaf(z2[r4], e3, a[8 + r4][3]);
        a[12 + r4][0] = fmaf(z3[r4], e0, a[12 + r4][0]);
        a[12 + r4][1] = fmaf(z3[r4], e1, a[12 + r4][1]);
        a[12 + r4][2] = fmaf(z3[r4], e2, a[12 + r4][2]);
        a[12 + r4][3] = fmaf(z3[r4], e3, a[12 + r4][3]);
      }
    }

    #pragma unroll
    for (int rr = 0; rr < 16; ++rr) {
      float bv = 3.4e38f; int bi = 0x7fffffff;
      #pragma unroll
      for (int q = 0; q < 4; ++q) {
        const int code = cz * 1024 + q * 256 + tid;
        const float D = __fsub_rn(__fadd_rn(zsq_sh[rr], esq[code]), __fmul_rn(2.f, a[rr][q]));
        if (D < bv) { bv = D; bi = code; }
      }
      #pragma unroll
      for (int off = 32; off; off >>= 1) {
        const float ov = __shfl_down(bv, off);
        const int   oi = __shfl_down(bi, off);
        if (ov < bv || (ov == bv && oi < bi)) { bv = ov; bi = oi; }
      }
      if (lane == 0) { rv[wv][rr] = bv; ri[wv][rr] = bi; }
    }
    __syncthreads();
    if (tid < 16) {
      const int fi = bb * 16 + tid;
      if (fi < n) {
        float fv = rv[0][tid]; int fx = ri[0][tid];
        #pragma unroll
        for (int q = 1; q < 4; ++q)
          if (rv[q][tid] < fv || (rv[q][tid] == fv && ri[q][tid] < fx)) { fv = rv[q][tid]; fx = ri[q][tid]; }
        rpv[fi * 8 + cz] = fv; rpi[fi * 8 + cz] = fx;
      }
    }
  }
}

// merge the 8 code-chunk partials per flagged row; FUSED hist + OUT_IDX write
__global__ void vq_rmerge(const int* __restrict__ flag, const int* __restrict__ cnt,
                          const float* __restrict__ rpv, const int* __restrict__ rpi,
                          int* __restrict__ idxf, int* __restrict__ hist,
                          float* __restrict__ out) {
  int n = *cnt; if (n > FLAGCAP) n = FLAGCAP;
  const int fi = blockIdx.x * blockDim.x + threadIdx.x;
  if (fi >= n) return;
  float bv = rpv[fi * 8]; int bi = rpi[fi * 8];
  #pragma unroll
  for (int c = 1; c < 8; ++c) {
    const float v = rpv[fi * 8 + c]; const int ix = rpi[fi * 8 + c];
    if (v < bv || (v == bv && ix < bi)) { bv = v; bi = ix; }
  }
  const int row = flag[fi];
  idxf[row] = bi;
  atomicAdd(hist + bi, 1);
  out[OUT_IDX + row] = (float)bi;
}

// prefix-scan of histogram + cluster-size output (1 block)
__global__ void vq_prefix(const float* __restrict__ ema_cs, int* __restrict__ hist,
                          int* __restrict__ base, int* __restrict__ cursor,
                          float* __restrict__ out) {
  __shared__ int ps[256];
  const int t = threadIdx.x;
  int loc[32]; int s = 0;
  #pragma unroll
  for (int j = 0; j < 32; ++j) { loc[j] = hist[t * 32 + j]; s += loc[j]; }
  ps[t] = s;
  __syncthreads();
  for (int off = 1; off < 256; off <<= 1) {
    const int v = (t >= off) ? ps[t - off] : 0;
    __syncthreads();
    ps[t] += v;
    __syncthreads();
  }
  int run = ps[t] - s;
  #pragma unroll
  for (int j = 0; j < 32; ++j) {
    const int i = t * 32 + j;
    base[i] = run; cursor[i] = run;
    out[OUT_CS + i] = 0.99f * ema_cs[i] + 0.01f * (float)loc[j];
    run += loc[j];
  }
}

__global__ void vq_slot(const int* __restrict__ idxf, int* __restrict__ cursor,
                        int* __restrict__ rowlist) {
  const int gi = blockIdx.x * blockDim.x + threadIdx.x;
  const int code = idxf[gi];
  const int p = atomicAdd(cursor + code, 1);
  rowlist[p] = gi;
}

// FUSED: per-code zq-write (zq = emb[code]) + loss partial + segmented z-sum
// + EMA + embeddings finalize. One wave per code.
__global__ void vq_embsum(const float* __restrict__ z, const float* __restrict__ emb,
                          const float* __restrict__ ema_sum,
                          const int* __restrict__ rowlist, const int* __restrict__ base,
                          const int* __restrict__ hist, float* __restrict__ out,
                          float* __restrict__ lossp) {
  const int code = blockIdx.x;
  const int lane = threadIdx.x;          // 64 threads = 1 wave
  const int b = base[code], n = hist[code];
  const float4 ev = *(const float4*)(emb + (size_t)code * DIM + lane * 4);
  float a0 = 0.f, a1 = 0.f, a2 = 0.f, a3 = 0.f, ls = 0.f;
  for (int i = 0; i < n; ++i) {
    const int row = rowlist[b + i];
    const float4 v = *(const float4*)(z + (size_t)row * DIM + lane * 4);
    a0 += v.x; a1 += v.y; a2 += v.z; a3 += v.w;
    const float d0 = ev.x - v.x, d1 = ev.y - v.y, d2 = ev.z - v.z, d3 = ev.w - v.w;
    ls = fmaf(d0, d0, fmaf(d1, d1, fmaf(d2, d2, fmaf(d3, d3, ls))));
    *(float4*)(out + OUT_ZQ + (size_t)row * DIM + lane * 4) = ev;  // z + (e-z) = e
  }
  #pragma unroll
  for (int off = 32; off; off >>= 1) ls += __shfl_down(ls, off);
  if (lane == 0) lossp[code] = ls;
  const float4 es = *(const float4*)(ema_sum + (size_t)code * DIM + lane * 4);
  const float s0 = 0.99f * es.x + 0.01f * a0;
  const float s1 = 0.99f * es.y + 0.01f * a1;
  const float s2 = 0.99f * es.z + 0.01f * a2;
  const float s3 = 0.99f * es.w + 0.01f * a3;
  float* sp = out + OUT_SUM + (size_t)code * DIM + lane * 4;   // odd base: scalar stores
  sp[0] = s0; sp[1] = s1; sp[2] = s2; sp[3] = s3;
  const float cs = out[OUT_CS + code] + 1e-5f;
  float* np_ = out + OUT_NEMB + (size_t)code * DIM + lane * 4;
  np_[0] = s0 / cs; np_[1] = s1 / cs; np_[2] = s2 / cs; np_[3] = s3 / cs;
}

// reduce 8192 per-code loss partials -> scalar (1 block)
__global__ void vq_lossred(const float* __restrict__ lossp, float* __restrict__ out) {
  __shared__ float lp[4];
  const int t = threadIdx.x;
  float ls = 0.f;
  #pragma unroll
  for (int j = 0; j < 8; ++j) {
    const float4 v = *(const float4*)(lossp + t * 32 + j * 4);
    ls += (v.x + v.y) + (v.z + v.w);
  }
  #pragma unroll
  for (int off = 32; off; off >>= 1) ls += __shfl_down(ls, off);
  if ((t & 63) == 0) lp[t >> 6] = ls;
  __syncthreads();
  if (t == 0)
    out[OUT_LOSS] = 0.25f * (((lp[0] + lp[1]) + (lp[2] + lp[3])) * (1.f / 8388608.f));
}

extern "C" void kernel_launch(void* const* d_in, const int* in_sizes, int n_in,
                              void* d_out, int out_size, void* d_ws, size_t ws_size,
                              hipStream_t stream) {
  const float* z      = (const float*)d_in[0];
  const float* emb    = (const float*)d_in[1];
  const float* emacs  = (const float*)d_in[2];
  const float* emasum = (const float*)d_in[3];
  float* out = (float*)d_out;
  float* ws  = (float*)d_ws;

  // ws layout (f32 words)
  float* esq     = ws;                        // 8192
  int*   idxf    = (int*)(ws + 8192);         // 32768
  int*   flag    = (int*)(ws + 40960);        // 16384
  int*   cnt     = (int*)(ws + 57344);        // 1 (+pad)
  int*   hist    = (int*)(ws + 57600);        // 8192
  int*   base    = (int*)(ws + 65792);        // 8192
  int*   cursor  = (int*)(ws + 73984);        // 8192
  int*   rowlist = (int*)(ws + 82176);        // 32768
  float* pb1     = ws + 114944;               // 4*32768 (lossp aliases after merge)
  int*   pi1     = (int*)(ws + 246016);       // 4*32768
  float* pb2     = ws + 377088;               // 4*32768
  short* esp2    = (short*)(ws + 508160);     // 8192*256 bf16, LDS-image tiled
  float* embT    = ws + 1556736;              // 256*8192 f32 transposed codebook
  float* rpv     = ws + 3653888;              // 16384*8 chunk partial values
  int*   rpi     = (int*)(ws + 3784960);      // 16384*8 chunk partial indices
  float* lossp   = pb1;                       // 8192 per-code loss partials

  vq_prep<<<1536, 256, 0, stream>>>(emb, esq, esp2, embT, hist, cnt);

  vq_mfma<<<1024, 256, 0, stream>>>(z, esp2, esq, pb1, pi1, pb2);
  vq_merge<<<N_TOK / 256, 256, 0, stream>>>(pb1, pi1, pb2, idxf, flag, cnt, hist, out);
  vq_rescan2<<<1024, 256, 0, stream>>>(z, embT, esq, flag, cnt, rpv, rpi);
  vq_rmerge<<<FLAGCAP / 256, 256, 0, stream>>>(flag, cnt, rpv, rpi, idxf, hist, out);

  vq_prefix<<<1, 256, 0, stream>>>(emacs, hist, base, cursor, out);
  vq_slot<<<N_TOK / 256, 256, 0, stream>>>(idxf, cursor, rowlist);
  vq_embsum<<<KC, 64, 0, stream>>>(z, emb, emasum, rowlist, base, hist, out, lossp);
  vq_lossred<<<1, 256, 0, stream>>>(lossp, out);
}